// Round 6
// baseline (73.927 us; speedup 1.0000x reference)
//
#include <hip/hip_runtime.h>
#include <hip/hip_bf16.h>

namespace {

constexpr int kHW = 36864;  // 192*192
constexpr int kFocalElems = 7744 * 80;

typedef __attribute__((ext_vector_type(8))) short bf16x8;
typedef __attribute__((ext_vector_type(4))) float f32x4;

__device__ __forceinline__ unsigned short f2bf(float x) {
  return __builtin_bit_cast(unsigned short, __float2bfloat16(x));
}

__device__ __forceinline__ float wave_sum(float v) {
#pragma unroll
  for (int off = 32; off; off >>= 1) v += __shfl_xor(v, off, 64);
  return v;
}

// ---------------------------------------------------------------------------
// Pre-gather: pick the 80 positive kernel rows per batch, convert to bf16,
// store densely as kbf[b][row80][256]. Grid (80, 2), block 128 (2 ch/thread).
// ---------------------------------------------------------------------------
__global__ __launch_bounds__(128) void gather_k(
    const float* __restrict__ k0, const float* __restrict__ k1,
    const float* __restrict__ k2, const float* __restrict__ k3,
    const float* __restrict__ k4,
    const int* __restrict__ q0, const int* __restrict__ q1,
    const int* __restrict__ q2, const int* __restrict__ q3,
    const int* __restrict__ q4,
    unsigned short* __restrict__ kbf) {
  const int b = blockIdx.y;
  const int row = blockIdx.x;        // 0..79
  const int l = row >> 4, p = row & 15;
  const float* kb[5] = {k0, k1, k2, k3, k4};
  const int* pb[5] = {q0, q1, q2, q3, q4};
  const int bg2[5] = {b * 1600, b * 1296, b * 576, b * 256, b * 144};
  const int pos = pb[l][b * 16 + p];
  const int ch = threadIdx.x * 2;
  const float2 kv = *(const float2*)(kb[l] + (size_t)(bg2[l] + pos) * 256 + ch);
  *(unsigned int*)&kbf[((size_t)b * 80 + row) * 256 + ch] =
      (unsigned int)f2bf(kv.x) | ((unsigned int)f2bf(kv.y) << 16);
}

// ---------------------------------------------------------------------------
// MFMA main kernel. Block = 256 thr (4 waves); each wave owns 16 pixels x all
// 80 rows. Grid = (576 pixel-tiles, 2 batches) = 1152 blocks (4.5 waves/SIMD).
// A-frags read directly from the pre-gathered bf16 K (L1/L2-resident, 40KB).
// B-frags: depth-2 software-pipelined scalar f32 loads (3 named buffers) +
// cvt to bf16. 5 M-tiles x 8 K-steps of mfma_f32_16x16x32_bf16 per wave.
// Epilogue: sigmoid, mt gather, 16-lane shfl reduce, LDS block-reduce, one
// atomic per (row, quantity) per block.
// ---------------------------------------------------------------------------
__global__ __launch_bounds__(256, 4) void solov2_main(
    const float* __restrict__ mask_out,
    const unsigned short* __restrict__ kbf,
    const float* __restrict__ mask_targets,
    float* __restrict__ acc) {
  const int b = blockIdx.y;
  const int lane = threadIdx.x & 63;
  const int wv = threadIdx.x >> 6;
  const int px16 = lane & 15;
  const int hi8 = (lane >> 4) * 8;
  const int pxl = blockIdx.x * 64 + wv * 16 + px16;

  const float* __restrict__ mop =
      mask_out + (size_t)b * 256 * kHW + (size_t)hi8 * kHW + pxl;
  // A-frag base for (mt, ks): + mt*16*256 + ks*32 (ushort units)
  const unsigned short* __restrict__ ka =
      kbf + ((size_t)b * 80 + px16) * 256 + hi8;

  __shared__ float bred[4][240];

  f32x4 a5[5];
#pragma unroll
  for (int mt = 0; mt < 5; ++mt) a5[mt] = (f32x4){0.f, 0.f, 0.f, 0.f};

  float pf0[8], pf1[8], pf2[8];

#define PF(BUF, KS)                                                         \
  {                                                                         \
    _Pragma("unroll") for (int j = 0; j < 8; ++j)                           \
        BUF[j] = mop[(size_t)((KS) * 32 + j) * kHW];                        \
  }

#define STEP(BUF, KS)                                                       \
  {                                                                         \
    bf16x8 bb;                                                              \
    _Pragma("unroll") for (int j = 0; j < 8; ++j)                           \
        bb[j] = (short)f2bf(BUF[j]);                                        \
    _Pragma("unroll") for (int mt = 0; mt < 5; ++mt) {                      \
      const bf16x8 af = *(const bf16x8*)(ka + mt * 4096 + (KS) * 32);       \
      a5[mt] = __builtin_amdgcn_mfma_f32_16x16x32_bf16(af, bb, a5[mt],      \
                                                       0, 0, 0);            \
    }                                                                       \
  }

  PF(pf0, 0);
  PF(pf1, 1);
  PF(pf2, 2); STEP(pf0, 0);
  PF(pf0, 3); STEP(pf1, 1);
  PF(pf1, 4); STEP(pf2, 2);
  PF(pf2, 5); STEP(pf0, 3);
  PF(pf0, 6); STEP(pf1, 4);
  PF(pf1, 7); STEP(pf2, 5);
  STEP(pf0, 6);
  STEP(pf1, 7);
#undef PF
#undef STEP

  // --- dice epilogue ---
  // D layout (m89): col = lane&15 (pixel), row80 = mt*16 + (lane>>4)*4 + reg.
  // Global flat row r = (row80>>4)*32 + b*16 + (row80&15); pairs with
  // mask_targets flat row r.
#pragma unroll
  for (int mt = 0; mt < 5; ++mt) {
#pragma unroll
    for (int j = 0; j < 4; ++j) {
      const int row80 = mt * 16 + (lane >> 4) * 4 + j;
      const int r = (row80 >> 4) * 32 + b * 16 + (row80 & 15);
      const float x0 = a5[mt][j];
      const float mp = 1.f / (1.f + __expf(-x0));
      const float tv = mask_targets[(size_t)r * kHW + pxl];
      float av = mp * tv;
      float bv = mp * mp;
      float cv = tv;  // binary targets: t*t == t
#pragma unroll
      for (int m = 1; m <= 8; m <<= 1) {
        av += __shfl_xor(av, m, 64);
        bv += __shfl_xor(bv, m, 64);
        cv += __shfl_xor(cv, m, 64);
      }
      if (px16 == 0) {
        bred[wv][row80] = av;
        bred[wv][80 + row80] = bv;
        bred[wv][160 + row80] = cv;
      }
    }
  }
  __syncthreads();
  if (threadIdx.x < 240) {
    const int q = threadIdx.x / 80;
    const int row80 = threadIdx.x - q * 80;
    const int r = (row80 >> 4) * 32 + b * 16 + (row80 & 15);
    const float s = bred[0][threadIdx.x] + bred[1][threadIdx.x] +
                    bred[2][threadIdx.x] + bred[3][threadIdx.x];
    unsafeAtomicAdd(&acc[q * 160 + r], s);
  }
}

// ---------------------------------------------------------------------------
// Focal loss over concatenated grid cells. N = 7744 cells x C = 80 classes.
// ---------------------------------------------------------------------------
__global__ __launch_bounds__(256) void focal_kernel(
    const float* __restrict__ c0, const float* __restrict__ c1,
    const float* __restrict__ c2, const float* __restrict__ c3,
    const float* __restrict__ c4,
    const int* __restrict__ t0, const int* __restrict__ t1,
    const int* __restrict__ t2, const int* __restrict__ t3,
    const int* __restrict__ t4,
    float* __restrict__ acc) {
  float term = 0.f, np = 0.f;
  for (int idx = blockIdx.x * 256 + threadIdx.x; idx < kFocalElems;
       idx += gridDim.x * 256) {
    const int n = idx / 80;       // cell index in concat order
    const int c = idx - n * 80;   // class
    int t;
    const float* crow;
    if (n < 3200) {
      t = t0[n]; crow = c0 + (size_t)n * 80;
    } else if (n < 5792) {
      const int o = n - 3200; t = t1[o]; crow = c1 + (size_t)o * 80;
    } else if (n < 6944) {
      const int o = n - 5792; t = t2[o]; crow = c2 + (size_t)o * 80;
    } else if (n < 7456) {
      const int o = n - 6944; t = t3[o]; crow = c3 + (size_t)o * 80;
    } else {
      const int o = n - 7456; t = t4[o]; crow = c4 + (size_t)o * 80;
    }
    if (t > -1) {
      float pv = crow[c];
      pv = fminf(fmaxf(pv, 1e-4f), 1.f - 1e-4f);
      const bool gm = (c == t);
      const float af = gm ? 0.25f : 0.75f;
      const float pt = gm ? pv : 1.f - pv;
      const float om = 1.f - pt;
      term = fmaf(af * om * om, -__logf(pt), term);
      if (c == 0) np += 1.f;
    }
  }
  term = wave_sum(term);
  np = wave_sum(np);
  __shared__ float st[8];
  const int wid = threadIdx.x >> 6;
  if ((threadIdx.x & 63) == 0) {
    st[wid] = term;
    st[4 + wid] = np;
  }
  __syncthreads();
  if (threadIdx.x == 0) {
    unsafeAtomicAdd(&acc[480], st[0] + st[1] + st[2] + st[3]);
    unsafeAtomicAdd(&acc[481], st[4] + st[5] + st[6] + st[7]);
  }
}

__global__ void zero_kernel(float* __restrict__ acc) {
  const int i = blockIdx.x * 256 + threadIdx.x;
  if (i < 482) acc[i] = 0.f;
}

__global__ __launch_bounds__(64) void finalize_kernel(
    const float* __restrict__ acc, float* __restrict__ out) {
  const int tid = threadIdx.x;
  float s = 0.f;
#pragma unroll
  for (int rr = 0; rr < 3; ++rr) {
    const int r = tid + rr * 64;
    if (r < 160) {
      const float a = acc[r];
      const float bb = acc[160 + r];
      const float cc = acc[320 + r];
      s += 1.f - 2.f * a / (bb + cc + 1e-4f);
    }
  }
  s = wave_sum(s);
  if (tid == 0) {
    out[0] = 3.0f * (s / 160.f);          // MASK_W * mask_loss
    out[1] = acc[480] / acc[481];         // CLS_W * cls_loss
  }
}

}  // namespace

extern "C" void kernel_launch(void* const* d_in, const int* in_sizes, int n_in,
                              void* d_out, int out_size, void* d_ws,
                              size_t ws_size, hipStream_t stream) {
  const float* mask_out = (const float*)d_in[0];
  const float* k[5];
  const float* cc[5];
  const int* pp[5];
  const int* tt[5];
  for (int i = 0; i < 5; ++i) {
    k[i] = (const float*)d_in[1 + 4 * i];
    cc[i] = (const float*)d_in[2 + 4 * i];
    pp[i] = (const int*)d_in[3 + 4 * i];
    tt[i] = (const int*)d_in[4 + 4 * i];
  }
  const float* mt = (const float*)d_in[21];
  float* acc = (float*)d_ws;                               // 482 floats
  unsigned short* kbf = (unsigned short*)((float*)d_ws + 512);  // 80KB bf16
  float* out = (float*)d_out;

  hipLaunchKernelGGL(zero_kernel, dim3(2), dim3(256), 0, stream, acc);
  hipLaunchKernelGGL(gather_k, dim3(80, 2), dim3(128), 0, stream,
                     k[0], k[1], k[2], k[3], k[4], pp[0], pp[1], pp[2], pp[3],
                     pp[4], kbf);
  hipLaunchKernelGGL(solov2_main, dim3(576, 2), dim3(256), 0, stream,
                     mask_out, kbf, mt, acc);
  hipLaunchKernelGGL(focal_kernel, dim3(320), dim3(256), 0, stream, cc[0],
                     cc[1], cc[2], cc[3], cc[4], tt[0], tt[1], tt[2], tt[3],
                     tt[4], acc);
  hipLaunchKernelGGL(finalize_kernel, dim3(1), dim3(64), 0, stream, acc, out);
}